// Round 1
// baseline (4757.435 us; speedup 1.0000x reference)
//
#include <hip/hip_runtime.h>

#define H_ 128
#define W_ 128
#define HW 16384
#define C_ 64
#define O_ 64
#define N_ 8
// weight transposed to wt[c][o][12] (k padded 9->12 so each o-row is 48B, float4-aligned)

__global__ void wtr_kernel(const float* __restrict__ w, float* __restrict__ wt) {
    int i = blockIdx.x * 256 + threadIdx.x;
    if (i >= C_ * O_ * 12) return;
    int k = i % 12;
    int o = (i / 12) % O_;
    int c = i / (12 * O_);
    float v = 0.0f;
    if (k < 9) v = w[(o * C_ + c) * 9 + k];
    wt[i] = v;
}

__global__ __launch_bounds__(256) void dcn_kernel(const float* __restrict__ x,
                                                  const float* __restrict__ off,
                                                  const float* __restrict__ wt,
                                                  float* __restrict__ out) {
    __shared__ float4 wbuf[2][192];

    const int tid = threadIdx.x;
    const int p = blockIdx.x * 256 + tid;
    const int wo = p & (W_ - 1);
    const int ho = (p >> 7) & (H_ - 1);
    const int n = p >> 14;

    // ---- per-pixel bilinear setup (hoisted out of channel loop) ----
    int i00[9];   // clamped base gather index y0c*W + x0c
    int dX[9];    // clamp(x0+1)-clamp(x0) in {0,1}
    int dYW[9];   // (clamp(y0+1)-clamp(y0))*W in {0,128}
    float wgt[9][4];  // bilinear weights with validity premultiplied

    const float* offp = off + (size_t)n * 18 * HW + ho * W_ + wo;
#pragma unroll
    for (int j = 0; j < 9; ++j) {
        const int kh = j / 3, kw = j % 3;
        const float oy = offp[(size_t)(2 * j) * HW];
        const float ox = offp[(size_t)(2 * j + 1) * HW];
        const float py = (float)(ho - 1 + kh) + oy;
        const float px = (float)(wo - 1 + kw) + ox;
        const float y0f = floorf(py);
        const float x0f = floorf(px);
        const float wy = py - y0f;
        const float wx = px - x0f;
        const int y0 = (int)y0f;
        const int x0 = (int)x0f;
        const int y1 = y0 + 1;
        const int x1 = x0 + 1;
        const bool vy0 = (y0 >= 0) & (y0 < H_);
        const bool vy1 = (y1 >= 0) & (y1 < H_);
        const bool vx0 = (x0 >= 0) & (x0 < W_);
        const bool vx1 = (x1 >= 0) & (x1 < W_);
        const int y0c = min(max(y0, 0), H_ - 1);
        const int y1c = min(max(y1, 0), H_ - 1);
        const int x0c = min(max(x0, 0), W_ - 1);
        const int x1c = min(max(x1, 0), W_ - 1);
        i00[j] = y0c * W_ + x0c;
        dX[j] = x1c - x0c;
        dYW[j] = (y1c - y0c) * W_;
        wgt[j][0] = (1.0f - wy) * (1.0f - wx) * ((vy0 & vx0) ? 1.0f : 0.0f);
        wgt[j][1] = (1.0f - wy) * wx * ((vy0 & vx1) ? 1.0f : 0.0f);
        wgt[j][2] = wy * (1.0f - wx) * ((vy1 & vx0) ? 1.0f : 0.0f);
        wgt[j][3] = wy * wx * ((vy1 & vx1) ? 1.0f : 0.0f);
    }

    float acc[O_];
#pragma unroll
    for (int o = 0; o < O_; ++o) acc[o] = 0.0f;

    const float* xn = x + (size_t)n * C_ * HW;
    const float4* wt4 = (const float4*)wt;

    // prologue: stage c=0 weight slice
    float4 r;
    if (tid < 192) {
        r = wt4[tid];
        wbuf[0][tid] = r;
    }
    __syncthreads();

    for (int c = 0; c < C_; ++c) {
        // prefetch next weight slice into registers
        if ((c + 1 < C_) && (tid < 192)) r = wt4[(c + 1) * 192 + tid];

        const float* xc = xn + c * HW;
        float s[9];
#pragma unroll
        for (int j = 0; j < 9; ++j) {
            const float* b = xc + i00[j];
            const float t00 = b[0];
            const float t01 = b[dX[j]];
            const float t10 = b[dYW[j]];
            const float t11 = b[dYW[j] + dX[j]];
            s[j] = wgt[j][0] * t00 + wgt[j][1] * t01 + wgt[j][2] * t10 + wgt[j][3] * t11;
        }

        const float4* wb = wbuf[c & 1];
#pragma unroll
        for (int o = 0; o < O_; ++o) {
            const float4 a = wb[o * 3 + 0];
            const float4 bq = wb[o * 3 + 1];
            const float4 cq = wb[o * 3 + 2];
            acc[o] += a.x * s[0] + a.y * s[1] + a.z * s[2] + a.w * s[3]
                    + bq.x * s[4] + bq.y * s[5] + bq.z * s[6] + bq.w * s[7]
                    + cq.x * s[8];
        }
        __syncthreads();
        if ((c + 1 < C_) && (tid < 192)) wbuf[(c + 1) & 1][tid] = r;
        __syncthreads();
    }

    float* op = out + (size_t)n * O_ * HW + ho * W_ + wo;
#pragma unroll
    for (int o = 0; o < O_; ++o) op[(size_t)o * HW] = acc[o];
}

extern "C" void kernel_launch(void* const* d_in, const int* in_sizes, int n_in,
                              void* d_out, int out_size, void* d_ws, size_t ws_size,
                              hipStream_t stream) {
    const float* x = (const float*)d_in[0];
    const float* off = (const float*)d_in[1];
    const float* w = (const float*)d_in[2];
    float* out = (float*)d_out;
    float* wt = (float*)d_ws;  // 64*64*12 floats = 192 KB

    wtr_kernel<<<(C_ * O_ * 12 + 255) / 256, 256, 0, stream>>>(w, wt);

    const int pixels = N_ * H_ * W_;  // 131072
    dcn_kernel<<<pixels / 256, 256, 0, stream>>>(x, off, wt, out);
}

// Round 2
// 93.770 us; speedup vs baseline: 50.7351x; 50.7351x over previous
//
#include <hip/hip_runtime.h>

#define H_ 128
#define W_ 128
#define HW 16384
#define C_ 64
#define O_ 64
#define N_ 8

typedef __attribute__((ext_vector_type(4))) float f32x4;
typedef __attribute__((ext_vector_type(8))) short short8;

__device__ __forceinline__ unsigned short f2bf(float f) {
    unsigned b = __float_as_uint(f);
    return (unsigned short)((b + 0x7fffu + ((b >> 16) & 1u)) >> 16);
}
__device__ __forceinline__ float bflo(unsigned u) { return __uint_as_float(u << 16); }
__device__ __forceinline__ float bfhi(unsigned u) { return __uint_as_float(u & 0xffff0000u); }
__device__ __forceinline__ unsigned packbf(float lo, float hi) {
    unsigned bl = __float_as_uint(lo), bh = __float_as_uint(hi);
    unsigned rl = (bl + 0x7fffu + ((bl >> 16) & 1u)) >> 16;
    unsigned rh = (bh + 0x7fffu + ((bh >> 16) & 1u)) & 0xffff0000u;
    return rh | rl;
}

// ---- prep 1: x NCHW fp32 -> xt NHWC bf16 ----
__global__ __launch_bounds__(256) void nchw2nhwc(const float* __restrict__ x,
                                                 unsigned short* __restrict__ xt) {
    const int bid = blockIdx.x;
    const int wt = bid & 3, h = (bid >> 2) & 127, n = bid >> 9;
    const int w0 = wt * 32;
    __shared__ unsigned short tile[32][65];
    const int tid = threadIdx.x;
    const int wl = tid & 31, cg = tid >> 5;  // cg in [0,8)
#pragma unroll
    for (int r = 0; r < 8; ++r) {
        const int c = cg * 8 + r;
        const float v = x[(((size_t)(n * 64 + c) * 128 + h) * 128) + w0 + wl];
        tile[wl][c] = f2bf(v);
    }
    __syncthreads();
    const int c2 = tid & 63, wg = tid >> 6;  // wg in [0,4)
#pragma unroll
    for (int r = 0; r < 8; ++r) {
        const int w = wg * 8 + r;
        xt[(((size_t)(n * 128 + h) * 128 + w0 + w) << 6) + c2] = tile[w][c2];
    }
}

// ---- prep 2: weight [O][C][3][3] fp32 -> B-fragment-packed bf16 ----
// frag index q = (j*2+h)*4 + ot ; ushort idx = q*512 + lane*8 + i
// lane: n_col = ot*16 + (lane&15) ; k: c = h*32 + (lane>>4)*8 + i ; j fixed per q
__global__ void bpack_kernel(const float* __restrict__ w, unsigned short* __restrict__ bp) {
    const int idx = blockIdx.x * 256 + threadIdx.x;
    if (idx >= 36864) return;
    const int i = idx & 7;
    const int lane = (idx >> 3) & 63;
    const int ot = (idx >> 9) & 3;
    const int h = (idx >> 11) & 1;
    const int j = idx >> 12;
    const int o = ot * 16 + (lane & 15);
    const int c = h * 32 + (lane >> 4) * 8 + i;
    bp[idx] = f2bf(w[(o * 64 + c) * 9 + j]);
}

// ---- main: implicit GEMM, one wave = 16-pixel x 64-o strip ----
__global__ __launch_bounds__(256) void dcn_mfma(const unsigned short* __restrict__ xt,
                                                const float* __restrict__ off,
                                                const unsigned short* __restrict__ bp,
                                                float* __restrict__ out) {
    __shared__ uint4 bsm4[4608];  // 73728 B: all B fragments
    const int tid = threadIdx.x;
    {
        const uint4* s = (const uint4*)bp;
        for (int i = tid; i < 4608; i += 256) bsm4[i] = s[i];
    }
    __syncthreads();
    const short8* bsm = (const short8*)bsm4;

    const int lane = tid & 63;
    const int wid = tid >> 6;
    const int lrow = lane & 15;   // M row (pixel within strip) / B col
    const int lgrp = lane >> 4;   // k-group

    for (int t = 0; t < 4; ++t) {
        const int strip = blockIdx.x * 16 + wid * 4 + t;
        const int n = strip >> 10;
        const int p0 = (strip & 1023) << 4;
        const int pix = p0 + lrow;
        const int ho = pix >> 7;
        const int wo = pix & 127;

        f32x4 acc0 = {0.f,0.f,0.f,0.f}, acc1 = {0.f,0.f,0.f,0.f};
        f32x4 acc2 = {0.f,0.f,0.f,0.f}, acc3 = {0.f,0.f,0.f,0.f};

        const float* offp = off + (size_t)n * 18 * HW + pix;
        const unsigned short* xn = xt + (size_t)n * (HW * 64);

        int j = 0;
        for (int kh = 0; kh < 3; ++kh) {
            for (int kw = 0; kw < 3; ++kw, ++j) {
                const float oy = offp[(size_t)(2 * j) * HW];
                const float ox = offp[(size_t)(2 * j + 1) * HW];
                const float py = (float)(ho - 1 + kh) + oy;
                const float px = (float)(wo - 1 + kw) + ox;
                const float y0f = floorf(py), x0f = floorf(px);
                const float wy = py - y0f, wx = px - x0f;
                const int y0 = (int)y0f, x0 = (int)x0f;
                const bool vy0 = (unsigned)y0 < (unsigned)H_;
                const bool vy1 = (unsigned)(y0 + 1) < (unsigned)H_;
                const bool vx0 = (unsigned)x0 < (unsigned)W_;
                const bool vx1 = (unsigned)(x0 + 1) < (unsigned)W_;
                const int y0c = min(max(y0, 0), H_ - 1);
                const int y1c = min(max(y0 + 1, 0), H_ - 1);
                const int x0c = min(max(x0, 0), W_ - 1);
                const int x1c = min(max(x0 + 1, 0), W_ - 1);
                const float w00 = (1.f - wy) * (1.f - wx) * ((vy0 & vx0) ? 1.f : 0.f);
                const float w01 = (1.f - wy) * wx * ((vy0 & vx1) ? 1.f : 0.f);
                const float w10 = wy * (1.f - wx) * ((vy1 & vx0) ? 1.f : 0.f);
                const float w11 = wy * wx * ((vy1 & vx1) ? 1.f : 0.f);

                const unsigned short* b00 = xn + (size_t)(y0c * W_ + x0c) * 64;
                const int dxo = (x1c - x0c) * 64;
                const int dyo = (y1c - y0c) * (W_ * 64);

#pragma unroll
                for (int h = 0; h < 2; ++h) {
                    const int c0 = h * 32 + lgrp * 8;
                    const uint4 u00 = *(const uint4*)(b00 + c0);
                    const uint4 u01 = *(const uint4*)(b00 + dxo + c0);
                    const uint4 u10 = *(const uint4*)(b00 + dyo + c0);
                    const uint4 u11 = *(const uint4*)(b00 + dyo + dxo + c0);
                    uint4 av;
                    av.x = packbf(w00*bflo(u00.x) + w01*bflo(u01.x) + w10*bflo(u10.x) + w11*bflo(u11.x),
                                  w00*bfhi(u00.x) + w01*bfhi(u01.x) + w10*bfhi(u10.x) + w11*bfhi(u11.x));
                    av.y = packbf(w00*bflo(u00.y) + w01*bflo(u01.y) + w10*bflo(u10.y) + w11*bflo(u11.y),
                                  w00*bfhi(u00.y) + w01*bfhi(u01.y) + w10*bfhi(u10.y) + w11*bfhi(u11.y));
                    av.z = packbf(w00*bflo(u00.z) + w01*bflo(u01.z) + w10*bflo(u10.z) + w11*bflo(u11.z),
                                  w00*bfhi(u00.z) + w01*bfhi(u01.z) + w10*bfhi(u10.z) + w11*bfhi(u11.z));
                    av.w = packbf(w00*bflo(u00.w) + w01*bflo(u01.w) + w10*bflo(u10.w) + w11*bflo(u11.w),
                                  w00*bfhi(u00.w) + w01*bfhi(u01.w) + w10*bfhi(u10.w) + w11*bfhi(u11.w));
                    union { uint4 u; short8 v; } A;
                    A.u = av;
                    const int fb = ((j * 2 + h) * 4) * 64 + lane;
                    acc0 = __builtin_amdgcn_mfma_f32_16x16x32_bf16(A.v, bsm[fb],       acc0, 0, 0, 0);
                    acc1 = __builtin_amdgcn_mfma_f32_16x16x32_bf16(A.v, bsm[fb + 64],  acc1, 0, 0, 0);
                    acc2 = __builtin_amdgcn_mfma_f32_16x16x32_bf16(A.v, bsm[fb + 128], acc2, 0, 0, 0);
                    acc3 = __builtin_amdgcn_mfma_f32_16x16x32_bf16(A.v, bsm[fb + 192], acc3, 0, 0, 0);
                }
            }
        }
        // epilogue: C/D layout col=lane&15 (o), row=(lane>>4)*4+r (pixel) -> contiguous float4
        float* opb = out + (size_t)n * (O_ * HW) + p0 + lgrp * 4;
        *(f32x4*)(opb + (size_t)(0 * 16 + lrow) * HW) = acc0;
        *(f32x4*)(opb + (size_t)(1 * 16 + lrow) * HW) = acc1;
        *(f32x4*)(opb + (size_t)(2 * 16 + lrow) * HW) = acc2;
        *(f32x4*)(opb + (size_t)(3 * 16 + lrow) * HW) = acc3;
    }
}

extern "C" void kernel_launch(void* const* d_in, const int* in_sizes, int n_in,
                              void* d_out, int out_size, void* d_ws, size_t ws_size,
                              hipStream_t stream) {
    const float* x = (const float*)d_in[0];
    const float* off = (const float*)d_in[1];
    const float* w = (const float*)d_in[2];
    float* out = (float*)d_out;

    unsigned short* bp = (unsigned short*)d_ws;                       // 73728 B
    unsigned short* xt = (unsigned short*)((char*)d_ws + 73728);      // 16.8 MB

    bpack_kernel<<<144, 256, 0, stream>>>(w, bp);
    nchw2nhwc<<<4096, 256, 0, stream>>>(x, xt);
    dcn_mfma<<<512, 256, 0, stream>>>(xt, off, bp, out);
}